// Round 2
// baseline (137.944 us; speedup 1.0000x reference)
//
#include <hip/hip_runtime.h>

// ws layout (floats):
// ws[0] = sum(part1*part2*part3)  (to be negated)
// ws[1] = num_pos
// ws[2] = count(pred > 0.3)
// ws[3] = wh smooth-l1 sum
// ws[4] = off smooth-l1 sum
// ws[5] = mask sum counted per-channel (i.e. 2 * sum(mask))

__device__ __forceinline__ void block_reduce_atomic3(float a, float b, float c,
                                                     float* ws, int i0, int i1, int i2) {
    #pragma unroll
    for (int off = 32; off > 0; off >>= 1) {
        a += __shfl_down(a, off, 64);
        b += __shfl_down(b, off, 64);
        c += __shfl_down(c, off, 64);
    }
    __shared__ float sa[8], sb[8], sc[8];
    int lane = threadIdx.x & 63;
    int wave = threadIdx.x >> 6;
    if (lane == 0) { sa[wave] = a; sb[wave] = b; sc[wave] = c; }
    __syncthreads();
    if (threadIdx.x == 0) {
        int nw = (blockDim.x + 63) >> 6;
        float ta = 0.f, tb = 0.f, tc = 0.f;
        for (int w = 0; w < nw; ++w) { ta += sa[w]; tb += sb[w]; tc += sc[w]; }
        atomicAdd(&ws[i0], ta);
        atomicAdd(&ws[i1], tb);
        atomicAdd(&ws[i2], tc);
    }
}

// Focal-loss element. pos case: (1-p)^2 * log(p); neg case: p^2 * (1-gt)^4 * log(1-p).
// arg = log argument; a = 1-arg is the part1 base in both cases.
// Counters go to the scalar pipe: ballot is wave-uniform -> SGPR accumulate.
__device__ __forceinline__ void hm_elem(float x, float gt, float& s_loss,
                                        unsigned& posc, unsigned& cntc) {
    bool pos = (gt == 1.0f);
    float e = __expf(-x);                         // v_mul + v_exp
    float p = __builtin_amdgcn_rcpf(1.0f + e);    // raw v_rcp_f32 (~1e-6 rel)
    p = fminf(fmaxf(p, 1e-4f), 1.0f - 1e-4f);     // v_med3
    float arg = pos ? p : 1.0f - p;               // log argument
    float a   = 1.0f - arg;                       // part1 base
    float b   = pos ? 1.0f : 1.0f - gt;           // part2 base
    float b2  = b * b;
    float l   = __logf(arg);                      // v_log + v_mul
    s_loss += (a * a) * (b2 * b2) * l;
    posc += (unsigned)__popcll(__ballot(pos));
    cntc += (unsigned)__popcll(__ballot(p > 0.3f));
}

__global__ void __launch_bounds__(256)
hm_loss_kernel(const float4* __restrict__ p4,
               const float4* __restrict__ g4,
               float* __restrict__ ws, long long N4) {
    long long tid = (long long)blockIdx.x * blockDim.x + threadIdx.x;
    long long NT  = (long long)gridDim.x * blockDim.x;

    float    s_loss = 0.f;
    unsigned posc = 0, cntc = 0;

    long long i = tid;
    // 4x unrolled, stride-interleaved: 8 coalesced dwordx4 loads in flight per thread.
    for (; i + 3 * NT < N4; i += 4 * NT) {
        float4 xp0 = p4[i];
        float4 xp1 = p4[i + NT];
        float4 xp2 = p4[i + 2 * NT];
        float4 xp3 = p4[i + 3 * NT];
        float4 xg0 = g4[i];
        float4 xg1 = g4[i + NT];
        float4 xg2 = g4[i + 2 * NT];
        float4 xg3 = g4[i + 3 * NT];

        hm_elem(xp0.x, xg0.x, s_loss, posc, cntc);
        hm_elem(xp0.y, xg0.y, s_loss, posc, cntc);
        hm_elem(xp0.z, xg0.z, s_loss, posc, cntc);
        hm_elem(xp0.w, xg0.w, s_loss, posc, cntc);
        hm_elem(xp1.x, xg1.x, s_loss, posc, cntc);
        hm_elem(xp1.y, xg1.y, s_loss, posc, cntc);
        hm_elem(xp1.z, xg1.z, s_loss, posc, cntc);
        hm_elem(xp1.w, xg1.w, s_loss, posc, cntc);
        hm_elem(xp2.x, xg2.x, s_loss, posc, cntc);
        hm_elem(xp2.y, xg2.y, s_loss, posc, cntc);
        hm_elem(xp2.z, xg2.z, s_loss, posc, cntc);
        hm_elem(xp2.w, xg2.w, s_loss, posc, cntc);
        hm_elem(xp3.x, xg3.x, s_loss, posc, cntc);
        hm_elem(xp3.y, xg3.y, s_loss, posc, cntc);
        hm_elem(xp3.z, xg3.z, s_loss, posc, cntc);
        hm_elem(xp3.w, xg3.w, s_loss, posc, cntc);
    }
    for (; i < N4; i += NT) {
        float4 xp = p4[i];
        float4 xg = g4[i];
        hm_elem(xp.x, xg.x, s_loss, posc, cntc);
        hm_elem(xp.y, xg.y, s_loss, posc, cntc);
        hm_elem(xp.z, xg.z, s_loss, posc, cntc);
        hm_elem(xp.w, xg.w, s_loss, posc, cntc);
    }

    // posc/cntc are wave-uniform; contribute once per wave via lane 0.
    int lane = threadIdx.x & 63;
    float fpos = (lane == 0) ? (float)posc : 0.f;
    float fcnt = (lane == 0) ? (float)cntc : 0.f;
    block_reduce_atomic3(s_loss, fpos, fcnt, ws, 0, 1, 2);
}

__device__ __forceinline__ float smooth_l1(float d) {
    float ad = fabsf(d);
    return (ad < 1.0f) ? 0.5f * d * d : ad - 0.5f;
}

__global__ void __launch_bounds__(256)
reg_loss_kernel(const float* __restrict__ wh_pred,  const float* __restrict__ wh_gt,
                const float* __restrict__ off_pred, const float* __restrict__ off_gt,
                const int* __restrict__ mask, const int* __restrict__ ind,
                float* __restrict__ ws, int BK, int K, int HW) {
    int t = blockIdx.x * blockDim.x + threadIdx.x;
    int nt = gridDim.x * blockDim.x;
    float s_wh = 0.f, s_off = 0.f, s_m = 0.f;

    for (int i = t; i < BK; i += nt) {
        int b   = i / K;
        float m = (float)mask[i];
        int idx = ind[i];
        const float* wb = wh_pred  + (size_t)b * 2 * HW;
        const float* ob = off_pred + (size_t)b * 2 * HW;
        #pragma unroll
        for (int c = 0; c < 2; ++c) {
            float gw = wb[(size_t)c * HW + idx];
            float tw = wh_gt[(size_t)i * 2 + c];
            s_wh += smooth_l1(gw * m - tw * m);

            float go = ob[(size_t)c * HW + idx];
            float to = off_gt[(size_t)i * 2 + c];
            s_off += smooth_l1(go * m - to * m);
        }
        s_m += 2.0f * m;
    }

    block_reduce_atomic3(s_wh, s_off, s_m, ws, 3, 4, 5);
}

__global__ void finalize_kernel(const float* __restrict__ ws, float* __restrict__ out) {
    float loss_sum = -ws[0];
    float num_pos  = ws[1];
    float fallback = fmaxf(ws[2], 1.0f);
    float denom    = (num_pos == 0.0f) ? fallback : num_pos;
    float hm_loss  = loss_sum / denom;

    float md       = ws[5] + 1e-4f;
    float wh_loss  = ws[3] / md;
    float off_loss = ws[4] / md;

    out[0] = hm_loss;
    out[1] = wh_loss;
    out[2] = off_loss;
    out[3] = 1.0f * hm_loss + 0.1f * wh_loss + 1.0f * off_loss;
}

extern "C" void kernel_launch(void* const* d_in, const int* in_sizes, int n_in,
                              void* d_out, int out_size, void* d_ws, size_t ws_size,
                              hipStream_t stream) {
    const float* hm_pred  = (const float*)d_in[0];
    const float* hm_gt    = (const float*)d_in[1];
    const float* wh_pred  = (const float*)d_in[2];
    const float* wh_gt    = (const float*)d_in[3];
    const float* off_pred = (const float*)d_in[4];
    const float* off_gt   = (const float*)d_in[5];
    const int*   mask     = (const int*)d_in[6];
    const int*   ind      = (const int*)d_in[7];
    float*       out      = (float*)d_out;
    float*       ws       = (float*)d_ws;

    long long N  = in_sizes[0];          // B*C*H*W
    int       BK = in_sizes[6];          // B*K
    const int K  = 128;                  // per reference setup
    int       B  = BK / K;
    int       HW = in_sizes[2] / (2 * B);

    hipMemsetAsync(d_ws, 0, 8 * sizeof(float), stream);

    hm_loss_kernel<<<2048, 256, 0, stream>>>((const float4*)hm_pred,
                                             (const float4*)hm_gt, ws, N >> 2);
    reg_loss_kernel<<<64, 256, 0, stream>>>(wh_pred, wh_gt, off_pred, off_gt,
                                            mask, ind, ws, BK, K, HW);
    finalize_kernel<<<1, 1, 0, stream>>>(ws, out);
}

// Round 3
// 76.870 us; speedup vs baseline: 1.7945x; 1.7945x over previous
//
#include <hip/hip_runtime.h>

// ws layout (floats), all written unconditionally every launch (no memset needed):
//   [0 .. 3*NB_HM)             hm partials per block:  {loss_sum, num_pos, cnt}
//   [REG_OFF .. REG_OFF+3*NB_REG) reg partials per block: {wh_sum, off_sum, mask_sum}
#define NB_HM   2048
#define NB_REG  64
#define REG_OFF (3 * NB_HM)

__device__ __forceinline__ float wave_sum(float v) {
    #pragma unroll
    for (int off = 32; off > 0; off >>= 1) v += __shfl_down(v, off, 64);
    return v;
}

// Block-level reduce of 3 values; thread 0 stores them to dst[0..2]. No atomics.
__device__ __forceinline__ void block_reduce_store3(float a, float b, float c,
                                                    float* __restrict__ dst) {
    a = wave_sum(a); b = wave_sum(b); c = wave_sum(c);
    __shared__ float sa[8], sb[8], sc[8];
    int lane = threadIdx.x & 63;
    int wave = threadIdx.x >> 6;
    if (lane == 0) { sa[wave] = a; sb[wave] = b; sc[wave] = c; }
    __syncthreads();
    if (threadIdx.x == 0) {
        int nw = blockDim.x >> 6;
        float ta = 0.f, tb = 0.f, tc = 0.f;
        for (int w = 0; w < nw; ++w) { ta += sa[w]; tb += sb[w]; tc += sc[w]; }
        dst[0] = ta; dst[1] = tb; dst[2] = tc;
    }
}

// Focal-loss element. pos case: (1-p)^2 * log(p); neg case: p^2 * (1-gt)^4 * log(1-p).
__device__ __forceinline__ void hm_elem(float x, float gt, float& s_loss,
                                        unsigned& posc, unsigned& cntc) {
    bool pos = (gt == 1.0f);
    float e = __expf(-x);
    float p = __builtin_amdgcn_rcpf(1.0f + e);
    p = fminf(fmaxf(p, 1e-4f), 1.0f - 1e-4f);
    float arg = pos ? p : 1.0f - p;
    float a   = 1.0f - arg;
    float b   = pos ? 1.0f : 1.0f - gt;
    float b2  = b * b;
    float l   = __logf(arg);
    s_loss += (a * a) * (b2 * b2) * l;
    posc += (unsigned)__popcll(__ballot(pos));
    cntc += (unsigned)__popcll(__ballot(p > 0.3f));
}

__global__ void __launch_bounds__(256)
hm_loss_kernel(const float4* __restrict__ p4,
               const float4* __restrict__ g4,
               float* __restrict__ ws, long long N4) {
    long long tid = (long long)blockIdx.x * blockDim.x + threadIdx.x;
    long long NT  = (long long)gridDim.x * blockDim.x;

    float    s_loss = 0.f;
    unsigned posc = 0, cntc = 0;

    long long i = tid;
    for (; i + 3 * NT < N4; i += 4 * NT) {
        float4 xp0 = p4[i];
        float4 xp1 = p4[i + NT];
        float4 xp2 = p4[i + 2 * NT];
        float4 xp3 = p4[i + 3 * NT];
        float4 xg0 = g4[i];
        float4 xg1 = g4[i + NT];
        float4 xg2 = g4[i + 2 * NT];
        float4 xg3 = g4[i + 3 * NT];

        hm_elem(xp0.x, xg0.x, s_loss, posc, cntc);
        hm_elem(xp0.y, xg0.y, s_loss, posc, cntc);
        hm_elem(xp0.z, xg0.z, s_loss, posc, cntc);
        hm_elem(xp0.w, xg0.w, s_loss, posc, cntc);
        hm_elem(xp1.x, xg1.x, s_loss, posc, cntc);
        hm_elem(xp1.y, xg1.y, s_loss, posc, cntc);
        hm_elem(xp1.z, xg1.z, s_loss, posc, cntc);
        hm_elem(xp1.w, xg1.w, s_loss, posc, cntc);
        hm_elem(xp2.x, xg2.x, s_loss, posc, cntc);
        hm_elem(xp2.y, xg2.y, s_loss, posc, cntc);
        hm_elem(xp2.z, xg2.z, s_loss, posc, cntc);
        hm_elem(xp2.w, xg2.w, s_loss, posc, cntc);
        hm_elem(xp3.x, xg3.x, s_loss, posc, cntc);
        hm_elem(xp3.y, xg3.y, s_loss, posc, cntc);
        hm_elem(xp3.z, xg3.z, s_loss, posc, cntc);
        hm_elem(xp3.w, xg3.w, s_loss, posc, cntc);
    }
    for (; i < N4; i += NT) {
        float4 xp = p4[i];
        float4 xg = g4[i];
        hm_elem(xp.x, xg.x, s_loss, posc, cntc);
        hm_elem(xp.y, xg.y, s_loss, posc, cntc);
        hm_elem(xp.z, xg.z, s_loss, posc, cntc);
        hm_elem(xp.w, xg.w, s_loss, posc, cntc);
    }

    int lane = threadIdx.x & 63;
    float fpos = (lane == 0) ? (float)posc : 0.f;
    float fcnt = (lane == 0) ? (float)cntc : 0.f;
    block_reduce_store3(s_loss, fpos, fcnt, &ws[3 * (size_t)blockIdx.x]);
}

__device__ __forceinline__ float smooth_l1(float d) {
    float ad = fabsf(d);
    return (ad < 1.0f) ? 0.5f * d * d : ad - 0.5f;
}

__global__ void __launch_bounds__(256)
reg_loss_kernel(const float* __restrict__ wh_pred,  const float* __restrict__ wh_gt,
                const float* __restrict__ off_pred, const float* __restrict__ off_gt,
                const int* __restrict__ mask, const int* __restrict__ ind,
                float* __restrict__ ws, int BK, int K, int HW) {
    int t = blockIdx.x * blockDim.x + threadIdx.x;
    int nt = gridDim.x * blockDim.x;
    float s_wh = 0.f, s_off = 0.f, s_m = 0.f;

    for (int i = t; i < BK; i += nt) {
        int b   = i / K;
        float m = (float)mask[i];
        int idx = ind[i];
        const float* wb = wh_pred  + (size_t)b * 2 * HW;
        const float* ob = off_pred + (size_t)b * 2 * HW;
        #pragma unroll
        for (int c = 0; c < 2; ++c) {
            float gw = wb[(size_t)c * HW + idx];
            float tw = wh_gt[(size_t)i * 2 + c];
            s_wh += smooth_l1(gw * m - tw * m);

            float go = ob[(size_t)c * HW + idx];
            float to = off_gt[(size_t)i * 2 + c];
            s_off += smooth_l1(go * m - to * m);
        }
        s_m += 2.0f * m;
    }

    block_reduce_store3(s_wh, s_off, s_m, &ws[REG_OFF + 3 * (size_t)blockIdx.x]);
}

__global__ void __launch_bounds__(1024)
reduce_finalize_kernel(const float* __restrict__ ws, float* __restrict__ out) {
    float a = 0.f, b = 0.f, c = 0.f, w = 0.f, o = 0.f, m = 0.f;
    for (int i = threadIdx.x; i < NB_HM; i += 1024) {
        a += ws[3 * i + 0];
        b += ws[3 * i + 1];
        c += ws[3 * i + 2];
    }
    if (threadIdx.x < 3 * NB_REG) {            // 192 threads read one float each
        float v = ws[REG_OFF + threadIdx.x];
        int r = threadIdx.x % 3;
        w = (r == 0) ? v : 0.f;
        o = (r == 1) ? v : 0.f;
        m = (r == 2) ? v : 0.f;
    }

    a = wave_sum(a); b = wave_sum(b); c = wave_sum(c);
    w = wave_sum(w); o = wave_sum(o); m = wave_sum(m);

    __shared__ float s[6][16];
    int lane = threadIdx.x & 63, wv = threadIdx.x >> 6;
    if (lane == 0) {
        s[0][wv] = a; s[1][wv] = b; s[2][wv] = c;
        s[3][wv] = w; s[4][wv] = o; s[5][wv] = m;
    }
    __syncthreads();
    if (threadIdx.x == 0) {
        float t[6];
        #pragma unroll
        for (int k = 0; k < 6; ++k) {
            float acc = 0.f;
            for (int q = 0; q < 16; ++q) acc += s[k][q];
            t[k] = acc;
        }
        float loss_sum = -t[0];
        float num_pos  = t[1];
        float fallback = fmaxf(t[2], 1.0f);
        float denom    = (num_pos == 0.0f) ? fallback : num_pos;
        float hm_loss  = loss_sum / denom;
        float md       = t[5] + 1e-4f;
        float wh_loss  = t[3] / md;
        float off_loss = t[4] / md;
        out[0] = hm_loss;
        out[1] = wh_loss;
        out[2] = off_loss;
        out[3] = hm_loss + 0.1f * wh_loss + off_loss;
    }
}

extern "C" void kernel_launch(void* const* d_in, const int* in_sizes, int n_in,
                              void* d_out, int out_size, void* d_ws, size_t ws_size,
                              hipStream_t stream) {
    const float* hm_pred  = (const float*)d_in[0];
    const float* hm_gt    = (const float*)d_in[1];
    const float* wh_pred  = (const float*)d_in[2];
    const float* wh_gt    = (const float*)d_in[3];
    const float* off_pred = (const float*)d_in[4];
    const float* off_gt   = (const float*)d_in[5];
    const int*   mask     = (const int*)d_in[6];
    const int*   ind      = (const int*)d_in[7];
    float*       out      = (float*)d_out;
    float*       ws       = (float*)d_ws;

    long long N  = in_sizes[0];          // B*C*H*W
    int       BK = in_sizes[6];          // B*K
    const int K  = 128;                  // per reference setup
    int       B  = BK / K;
    int       HW = in_sizes[2] / (2 * B);

    hm_loss_kernel<<<NB_HM, 256, 0, stream>>>((const float4*)hm_pred,
                                              (const float4*)hm_gt, ws, N >> 2);
    reg_loss_kernel<<<NB_REG, 256, 0, stream>>>(wh_pred, wh_gt, off_pred, off_gt,
                                                mask, ind, ws, BK, K, HW);
    reduce_finalize_kernel<<<1, 1024, 0, stream>>>(ws, out);
}